// Round 1
// 289.927 us; speedup vs baseline: 1.1167x; 1.1167x over previous
//
#include <hip/hip_runtime.h>
#include <hip/hip_bf16.h>

typedef __attribute__((ext_vector_type(8))) short short8;
typedef __attribute__((ext_vector_type(4))) short bf16x4;
typedef __attribute__((ext_vector_type(4))) float f32x4;

#define DM 1024
#define NH 16
#define HS 64
#define SEQL 2048

__device__ __forceinline__ float bf2f(short s) {
  unsigned u = ((unsigned)(unsigned short)s) << 16;
  float f;
  __builtin_memcpy(&f, &u, 4);
  return f;
}
__device__ __forceinline__ short f2bf(float f) {
  unsigned u;
  __builtin_memcpy(&u, &f, 4);
  u = u + 0x7FFFu + ((u >> 16) & 1u);   // RNE
  return (short)(u >> 16);
}

// async global->LDS, 16B per lane. LDS dest must be wave-uniform base + lane*16
// (our per-thread lds addr is base + tid*16, which satisfies that per wave).
__device__ __forceinline__ void gl2lds16(const void* g, void* l) {
  __builtin_amdgcn_global_load_lds(
      (const __attribute__((address_space(1))) void*)g,
      (__attribute__((address_space(3))) void*)l, 16, 0, 0);
}

// 8x f32 -> short8 bf16 via v_cvt_pk_bf16_f32 (RNE, 4 instrs instead of 24 int-alu)
__device__ __forceinline__ short8 cvt_pk8(f32x4 lo, f32x4 hi) {
  union { short8 s8; unsigned u[4]; } r;
  asm("v_cvt_pk_bf16_f32 %0, %1, %2" : "=v"(r.u[0]) : "v"(lo[0]), "v"(lo[1]));
  asm("v_cvt_pk_bf16_f32 %0, %1, %2" : "=v"(r.u[1]) : "v"(lo[2]), "v"(lo[3]));
  asm("v_cvt_pk_bf16_f32 %0, %1, %2" : "=v"(r.u[2]) : "v"(hi[0]), "v"(hi[1]));
  asm("v_cvt_pk_bf16_f32 %0, %1, %2" : "=v"(r.u[3]) : "v"(hi[2]), "v"(hi[3]));
  return r.s8;
}

// ---- weight pack (LDS-tiled transpose): Wt[h][hs][dm] = bf16(W[h][dm][hs]) ----
__global__ __launch_bounds__(256) void pack_w_kernel(
    const float* __restrict__ Wq, const float* __restrict__ Wk, const float* __restrict__ Wv,
    short* __restrict__ WtQ, short* __restrict__ WtK, short* __restrict__ WtV) {
  const float* W = (blockIdx.z == 0) ? Wq : (blockIdx.z == 1) ? Wk : Wv;
  short* Wt      = (blockIdx.z == 0) ? WtQ : (blockIdx.z == 1) ? WtK : WtV;
  __shared__ short Ts[64][73];                 // [dm-within][hs], odd pad
  const int h = blockIdx.y, dm0 = blockIdx.x * 64;
  const int tid = threadIdx.x;
#pragma unroll
  for (int p = 0; p < 4; ++p) {                // read 64dm x 64hs as float4 (1024 chunks)
    int idx = p * 256 + tid;
    int i = idx >> 4, hsq = (idx & 15) * 4;    // coalesced float4 reads, hs fastest
    f32x4 v = *(const f32x4*)&W[((h << 10) + dm0 + i) * 64 + hsq];
#pragma unroll
    for (int j = 0; j < 4; ++j) Ts[i][hsq + j] = f2bf(v[j]);
  }
  __syncthreads();
  {                                            // write: 64 hs x 4 dm-quads = exactly 256 items
    int hs = tid >> 2, dmq = (tid & 3) * 16;
    short8 o0, o1;
#pragma unroll
    for (int j = 0; j < 8; ++j) { o0[j] = Ts[dmq + j][hs]; o1[j] = Ts[dmq + 8 + j][hs]; }
    short* dst = &Wt[((h * 64 + hs) << 10) + dm0 + dmq];
    *(short8*)dst = o0;
    *(short8*)(dst + 8) = o1;
  }
}

// ---- fp32 -> bf16 bulk convert (used for Wo after attn frees the Qb region) ----
__global__ __launch_bounds__(256) void cvt_bf16_kernel(const float* __restrict__ in,
                                                       short* __restrict__ out) {
  int i = blockIdx.x * 256 + threadIdx.x;      // one short8 per thread
  const f32x4* p = (const f32x4*)(in + (size_t)i * 8);
  f32x4 a = p[0], b = p[1];
  short8 o;
#pragma unroll
  for (int j = 0; j < 4; ++j) { o[j] = f2bf(a[j]); o[4 + j] = f2bf(b[j]); }
  *(short8*)(out + (size_t)i * 8) = o;
}

// ---------------- GEMM: C[m][n] = sum_k A[m][k]*Bt[n][k] + bias[n] ----------------
// m97 structure: 128-row tile, BK=32, global_load_lds width-16 staging into LINEAR LDS.
// Rule-21 XOR swizzle: inverse-swizzled GLOBAL source + swizzled ds_read (LDS dest linear)
// -> fragment b128 reads are bank-conflict-free within each 8-lane phase.
// AF32: A operand is fp32 in global; staged as fp32, converted to bf16 at frag read
//       via v_cvt_pk_bf16_f32 (16/wave/K-step instead of ~96 int-ALU on staging path).
// NB = per-wave n-fragment count: 4 -> TN=128 (QKV, 768 blocks), 2 -> TN=64 (out-proj, 512 blocks).
// mode 0: bf16 [b][h][s][64];  mode 2: bf16 [b][h][d][s];  mode 1: fp32 row-major [m][1024]
struct GemmArgs {
  const void* A;
  const void* Bt;
  const float* bias;
  short* out;
  float* outf;
  int mode;
};

template <bool AF32, int NB>
__global__ __launch_bounds__(256) void gemm_bt_kernel(GemmArgs g0, GemmArgs g1, GemmArgs g2) {
  GemmArgs g = (blockIdx.z == 0) ? g0 : (blockIdx.z == 1) ? g1 : g2;
  const int K = 1024;
  const int TN = NB * 32;
  const int m0 = blockIdx.x * 128;
  const int n0 = blockIdx.y * TN;
  const int tid = threadIdx.x;
  const int w = tid >> 6, l = tid & 63, lr = l & 15, lk = l >> 4;
  const int wr = w >> 1, wc = w & 1;

  // A tile 128x32 (fp32 or bf16), B tile TNx32 bf16 — both LINEAR (global_load_lds dest)
  __shared__ __align__(16) char AsRaw[128 * 32 * (AF32 ? 4 : 2)];
  __shared__ __align__(16) short Bs[TN * 32];
  float* Asf = (float*)AsRaw;
  short* As  = (short*)AsRaw;

  // read-side swizzle constants (row bits [3:0] == lr bits for all fragment rows)
  const int swz3 = lr & 7;                           // fp32 tile: 8 slots of 16B per 128B row
  const int swz2 = (lr & 3) ^ ((lr >> 2) & 3);       // bf16 tile: 4 slots of 16B per 64B row

  f32x4 acc[4][NB];
#pragma unroll
  for (int i = 0; i < 4; ++i)
#pragma unroll
    for (int j = 0; j < NB; ++j) acc[i][j] = (f32x4){0.f, 0.f, 0.f, 0.f};

  for (int k0 = 0; k0 < K; k0 += 32) {
    __syncthreads();                               // prev ds_reads done before overwrite
    // ---- stage A ----
    if constexpr (AF32) {
      const float* Af = (const float*)g.A;
#pragma unroll
      for (int i = 0; i < 4; ++i) {                // 128x32 fp32 = 1024 16B chunks
        int c = i * 256 + tid;
        int row = c >> 3, s = c & 7;
        int gc = (s ^ (row & 7)) * 4;              // inverse-swizzled source column
        gl2lds16(&Af[(size_t)(m0 + row) * K + k0 + gc], &Asf[c * 4]);
      }
    } else {
      const short* Ah = (const short*)g.A;
#pragma unroll
      for (int i = 0; i < 2; ++i) {                // 128x32 bf16 = 512 16B chunks
        int c = i * 256 + tid;
        int row = c >> 2, s = c & 3;
        int gc = (s ^ ((row & 3) ^ ((row >> 2) & 3))) * 8;
        gl2lds16(&Ah[(size_t)(m0 + row) * K + k0 + gc], &As[c * 8]);
      }
    }
    // ---- stage B (bf16 always) ----
    {
      const short* Bh = (const short*)g.Bt;
#pragma unroll
      for (int i = 0; i < TN / 64; ++i) {          // TNx32 bf16 = TN*4 16B chunks
        int c = i * 256 + tid;
        int row = c >> 2, s = c & 3;
        int gc = (s ^ ((row & 3) ^ ((row >> 2) & 3))) * 8;
        gl2lds16(&Bh[(size_t)(n0 + row) * K + k0 + gc], &Bs[c * 8]);
      }
    }
    __syncthreads();                               // compiler drains vmcnt(0) here

    // ---- fragments (swizzled reads) ----
    short8 af[4], bfr[NB];
#pragma unroll
    for (int t = 0; t < 4; ++t) {
      int row = wr * 64 + t * 16 + lr;
      if constexpr (AF32) {
        int base = row * 32;                       // floats
        f32x4 lo = *(const f32x4*)&Asf[base + (((lk << 1)    ) ^ swz3) * 4];
        f32x4 hi = *(const f32x4*)&Asf[base + (((lk << 1) | 1) ^ swz3) * 4];
        af[t] = cvt_pk8(lo, hi);
      } else {
        af[t] = *(const short8*)&As[row * 32 + (lk ^ swz2) * 8];
      }
    }
#pragma unroll
    for (int t = 0; t < NB; ++t) {
      int row = wc * (NB * 16) + t * 16 + lr;
      bfr[t] = *(const short8*)&Bs[row * 32 + (lk ^ swz2) * 8];
    }
#pragma unroll
    for (int ti = 0; ti < 4; ++ti)
#pragma unroll
      for (int tj = 0; tj < NB; ++tj)
        acc[ti][tj] = __builtin_amdgcn_mfma_f32_16x16x32_bf16(af[ti], bfr[tj], acc[ti][tj], 0, 0, 0);
  }

#pragma unroll
  for (int ti = 0; ti < 4; ++ti)
#pragma unroll
    for (int tj = 0; tj < NB; ++tj) {
      int n = n0 + wc * (NB * 16) + tj * 16 + lr;
      float bia = g.bias[n];
      int mb = m0 + wr * 64 + ti * 16 + lk * 4;        // C rows: mb..mb+3
      if (g.mode == 2) {
        bf16x4 o;
#pragma unroll
        for (int r = 0; r < 4; ++r) o[r] = f2bf(acc[ti][tj][r] + bia);
        // [b][h][d][s]: 4 consecutive s -> one 8B store
        *(bf16x4*)&g.out[((mb >> 11) * 16 + (n >> 6)) * (SEQL * HS) + (n & 63) * SEQL + (mb & 2047)] = o;
      } else {
#pragma unroll
        for (int r = 0; r < 4; ++r) {
          int m = mb + r;
          float v = acc[ti][tj][r] + bia;
          if (g.mode == 0) {
            g.out[((m >> 11) * 16 + (n >> 6)) * (SEQL * HS) + (m & 2047) * HS + (n & 63)] = f2bf(v);
          } else {
            g.outf[(size_t)m * DM + n] = v;
          }
        }
      }
    }
}

// ---------------- flash attention (S^T form): per (b,h), O = softmax(Q K^T / 8) V ----------------
// (unchanged this round)
__global__ __launch_bounds__(256, 4) void attn_kernel(const short* __restrict__ Qg, const short* __restrict__ Kg,
                                                      const short* __restrict__ Vtg, short* __restrict__ Og) {
  const int qt = blockIdx.x;   // 32 q-tiles of 64 rows
  const int bh = blockIdx.y;   // 32 (b,h)
  const short* Qp = Qg + bh * SEQL * HS;
  const short* Kp = Kg + bh * SEQL * HS;
  const short* Vp = Vtg + bh * HS * SEQL;   // [d][s]
  const int tid = threadIdx.x, w = tid >> 6, l = tid & 63, lr = l & 15, lk = l >> 4;
  const int qw = qt * 64 + w * 16;          // wave's q base (16 rows)

  __shared__ __align__(16) short Ks[128][72];      // K tile [kv][d]
  __shared__ __align__(16) short Vt[64][136];      // V^T tile [d][kv]

  short8 qf[2];
#pragma unroll
  for (int kk = 0; kk < 2; ++kk) {
    short8 qr = *(const short8*)&Qp[(qw + lr) * HS + kk * 32 + lk * 8];
#pragma unroll
    for (int j = 0; j < 8; ++j) qf[kk][j] = f2bf(bf2f(qr[j]) * 0.125f);
  }

  float mrow = -1e30f, lrow = 0.f;
  f32x4 accO[4];
#pragma unroll
  for (int t = 0; t < 4; ++t) accO[t] = (f32x4){0.f, 0.f, 0.f, 0.f};

  for (int kv = 0; kv < 16; ++kv) {
    __syncthreads();
#pragma unroll
    for (int i = 0; i < 4; ++i) {            // K tile: 128x64, coalesced b128
      int q = tid + i * 256;
      int row = q >> 3, col = (q & 7) * 8;
      *(short8*)&Ks[row][col] = *(const short8*)&Kp[(kv * 128 + row) * HS + col];
    }
#pragma unroll
    for (int i = 0; i < 4; ++i) {            // V^T tile: 64x128, coalesced b128
      int q = tid + i * 256;
      int d = q >> 4, sc = (q & 15) * 8;
      *(short8*)&Vt[d][sc] = *(const short8*)&Vp[d * SEQL + kv * 128 + sc];
    }
    __syncthreads();

    f32x4 accS[8];
#pragma unroll
    for (int tj = 0; tj < 8; ++tj) {
      short8 a0 = *(const short8*)&Ks[tj * 16 + lr][lk * 8];
      short8 a1 = *(const short8*)&Ks[tj * 16 + lr][32 + lk * 8];
      f32x4 z = (f32x4){0.f, 0.f, 0.f, 0.f};
      z = __builtin_amdgcn_mfma_f32_16x16x32_bf16(a0, qf[0], z, 0, 0, 0);
      accS[tj] = __builtin_amdgcn_mfma_f32_16x16x32_bf16(a1, qf[1], z, 0, 0, 0);
    }

    float mx = accS[0][0];
#pragma unroll
    for (int tj = 0; tj < 8; ++tj)
#pragma unroll
      for (int r = 0; r < 4; ++r) mx = fmaxf(mx, accS[tj][r]);
    mx = fmaxf(mx, __shfl_xor(mx, 16));
    mx = fmaxf(mx, __shfl_xor(mx, 32));
    float mn = fmaxf(mrow, mx);
    float alpha = __expf(mrow - mn);
    float ps = 0.f;
#pragma unroll
    for (int tj = 0; tj < 8; ++tj)
#pragma unroll
      for (int r = 0; r < 4; ++r) {
        float p = __expf(accS[tj][r] - mn);
        accS[tj][r] = p;
        ps += p;
      }
    ps += __shfl_xor(ps, 16);
    ps += __shfl_xor(ps, 32);
    lrow = lrow * alpha + ps;
    mrow = mn;
#pragma unroll
    for (int t = 0; t < 4; ++t) accO[t] *= alpha;

#pragma unroll
    for (int st = 0; st < 8; ++st) {
      bf16x4 bfrag;
#pragma unroll
      for (int r = 0; r < 4; ++r) bfrag[r] = f2bf(accS[st][r]);
#pragma unroll
      for (int tjd = 0; tjd < 4; ++tjd) {
        bf16x4 afrag = *(const bf16x4*)&Vt[tjd * 16 + lr][st * 16 + lk * 4];
        accO[tjd] = __builtin_amdgcn_mfma_f32_16x16x16bf16_1k(afrag, bfrag, accO[tjd], 0, 0, 0);
      }
    }
  }

  const int b = bh >> 4, h = bh & 15;
  float inv = 1.f / lrow;
  size_t rowbase = (size_t)(b * SEQL + qw + lr) * DM + h * HS;
#pragma unroll
  for (int tjd = 0; tjd < 4; ++tjd) {
    bf16x4 o;
#pragma unroll
    for (int r = 0; r < 4; ++r) o[r] = f2bf(accO[tjd][r] * inv);
    *(bf16x4*)&Og[rowbase + tjd * 16 + lk * 4] = o;
  }
}

extern "C" void kernel_launch(void* const* d_in, const int* in_sizes, int n_in,
                              void* d_out, int out_size, void* d_ws, size_t ws_size,
                              hipStream_t stream) {
  const float* query  = (const float*)d_in[0];
  const float* key_in = (const float*)d_in[1];
  const float* value  = (const float*)d_in[2];
  const float* Wq = (const float*)d_in[3];
  const float* Wk = (const float*)d_in[4];
  const float* Wv = (const float*)d_in[5];
  const float* bq = (const float*)d_in[6];
  const float* bk = (const float*)d_in[7];
  const float* bv = (const float*)d_in[8];
  const float* Wo = (const float*)d_in[9];
  const float* bo = (const float*)d_in[10];
  float* out = (float*)d_out;          // FP32 output

  // ws layout (shorts), 32 MB total:
  //   [0,4M) Qb [b][h][s][64]  (reused as Wob bf16 after attn);
  //   [4M,8M) Kb; [8M,12M) Vbt [b][h][64][s];
  //   [12M,16M) X: WtQ/WtK/WtV (QKV-GEMM phase) then At [4096][1024] (attn phase)
  short* ws  = (short*)d_ws;
  short* Qb  = ws;
  short* Kb  = Qb + (4 << 20);
  short* Vbt = Kb + (4 << 20);
  short* X   = Vbt + (4 << 20);
  short* WtQ = X;
  short* WtK = WtQ + (1 << 20);
  short* WtV = WtK + (1 << 20);
  short* At  = X;
  short* Wob = Qb;                     // Qb is dead once attn completes

  pack_w_kernel<<<dim3(16, 16, 3), 256, 0, stream>>>(Wq, Wk, Wv, WtQ, WtK, WtV);

  GemmArgs gq{query, WtQ, bq, Qb, nullptr, 0}, gk{key_in, WtK, bk, Kb, nullptr, 0},
           gv{value, WtV, bv, Vbt, nullptr, 2};
  gemm_bt_kernel<true, 4><<<dim3(32, 8, 3), 256, 0, stream>>>(gq, gk, gv);

  attn_kernel<<<dim3(32, 32), 256, 0, stream>>>(Qb, Kb, Vbt, At);

  cvt_bf16_kernel<<<dim3(512), 256, 0, stream>>>(Wo, Wob);   // 1M elems -> bf16

  GemmArgs go{At, Wob, bo, nullptr, out, 1};
  gemm_bt_kernel<false, 2><<<dim3(32, 16, 1), 256, 0, stream>>>(go, go, go);
}

// Round 2
// 259.704 us; speedup vs baseline: 1.2467x; 1.1164x over previous
//
#include <hip/hip_runtime.h>
#include <hip/hip_bf16.h>

typedef __attribute__((ext_vector_type(8))) short short8;
typedef __attribute__((ext_vector_type(4))) short bf16x4;
typedef __attribute__((ext_vector_type(4))) float f32x4;

#define DM 1024
#define NH 16
#define HS 64
#define SEQL 2048

__device__ __forceinline__ float bf2f(short s) {
  unsigned u = ((unsigned)(unsigned short)s) << 16;
  float f;
  __builtin_memcpy(&f, &u, 4);
  return f;
}
__device__ __forceinline__ short f2bf(float f) {
  unsigned u;
  __builtin_memcpy(&u, &f, 4);
  u = u + 0x7FFFu + ((u >> 16) & 1u);   // RNE
  return (short)(u >> 16);
}

// async global->LDS, 16B per lane (LDS dest = wave-uniform base + lane*16 per wave).
__device__ __forceinline__ void gl2lds16(const void* g, void* l) {
  __builtin_amdgcn_global_load_lds(
      (const __attribute__((address_space(1))) void*)g,
      (__attribute__((address_space(3))) void*)l, 16, 0, 0);
}

// 8x f32 -> short8 bf16 via v_cvt_pk_bf16_f32 (RNE)
__device__ __forceinline__ short8 cvt_pk8(f32x4 lo, f32x4 hi) {
  union { short8 s8; unsigned u[4]; } r;
  asm("v_cvt_pk_bf16_f32 %0, %1, %2" : "=v"(r.u[0]) : "v"(lo[0]), "v"(lo[1]));
  asm("v_cvt_pk_bf16_f32 %0, %1, %2" : "=v"(r.u[1]) : "v"(lo[2]), "v"(lo[3]));
  asm("v_cvt_pk_bf16_f32 %0, %1, %2" : "=v"(r.u[2]) : "v"(hi[0]), "v"(hi[1]));
  asm("v_cvt_pk_bf16_f32 %0, %1, %2" : "=v"(r.u[3]) : "v"(hi[2]), "v"(hi[3]));
  return r.s8;
}

// ---- weight pack (LDS-tiled transpose): Wt[h][hs][dm] = bf16(W[h][dm][hs]) ----
__global__ __launch_bounds__(256) void pack_w_kernel(
    const float* __restrict__ Wq, const float* __restrict__ Wk, const float* __restrict__ Wv,
    short* __restrict__ WtQ, short* __restrict__ WtK, short* __restrict__ WtV) {
  const float* W = (blockIdx.z == 0) ? Wq : (blockIdx.z == 1) ? Wk : Wv;
  short* Wt      = (blockIdx.z == 0) ? WtQ : (blockIdx.z == 1) ? WtK : WtV;
  __shared__ short Ts[64][73];                 // [dm-within][hs], odd pad
  const int h = blockIdx.y, dm0 = blockIdx.x * 64;
  const int tid = threadIdx.x;
#pragma unroll
  for (int p = 0; p < 4; ++p) {                // read 64dm x 64hs as float4 (1024 chunks)
    int idx = p * 256 + tid;
    int i = idx >> 4, hsq = (idx & 15) * 4;    // coalesced float4 reads, hs fastest
    f32x4 v = *(const f32x4*)&W[((h << 10) + dm0 + i) * 64 + hsq];
#pragma unroll
    for (int j = 0; j < 4; ++j) Ts[i][hsq + j] = f2bf(v[j]);
  }
  __syncthreads();
  {                                            // write: 64 hs x 4 dm-quads = exactly 256 items
    int hs = tid >> 2, dmq = (tid & 3) * 16;
    short8 o0, o1;
#pragma unroll
    for (int j = 0; j < 8; ++j) { o0[j] = Ts[dmq + j][hs]; o1[j] = Ts[dmq + 8 + j][hs]; }
    short* dst = &Wt[((h * 64 + hs) << 10) + dm0 + dmq];
    *(short8*)dst = o0;
    *(short8*)(dst + 8) = o1;
  }
}

// ---- fp32 -> bf16 bulk convert (used for Wo after attn frees the Qb region) ----
__global__ __launch_bounds__(256) void cvt_bf16_kernel(const float* __restrict__ in,
                                                       short* __restrict__ out) {
  int i = blockIdx.x * 256 + threadIdx.x;      // one short8 per thread
  const f32x4* p = (const f32x4*)(in + (size_t)i * 8);
  f32x4 a = p[0], b = p[1];
  short8 o;
#pragma unroll
  for (int j = 0; j < 4; ++j) { o[j] = f2bf(a[j]); o[4 + j] = f2bf(b[j]); }
  *(short8*)(out + (size_t)i * 8) = o;
}

// ---------------- GEMM: C[m][n] = sum_k A[m][k]*Bt[n][k] + bias[n] ----------------
// 2-phase double-buffered (T3 minimum recipe): per K-step issue STAGE(next) first,
// then ds_read+MFMA(current), then ONE __syncthreads (drains vmcnt for next tile).
// Load latency of tile t+1 hides under compute of tile t.
// Rule-21 XOR swizzle: inverse-swizzled GLOBAL source + swizzled ds_read (LDS dest linear).
// AF32: A staged as fp32 via global_load_lds, converted at frag read with v_cvt_pk_bf16_f32.
// NB = per-wave n-fragments: 4 -> TN=128 (QKV), 2 -> TN=64 (out-proj, 512 blocks).
// mode 0: bf16 [b][h][s][64];  mode 2: bf16 [b][h][d][s];  mode 1: fp32 row-major [m][1024]
struct GemmArgs {
  const void* A;
  const void* Bt;
  const float* bias;
  short* out;
  float* outf;
  int mode;
};

template <bool AF32, int NB>
__global__ __launch_bounds__(256) void gemm_bt_kernel(GemmArgs g0, GemmArgs g1, GemmArgs g2) {
  GemmArgs g = (blockIdx.z == 0) ? g0 : (blockIdx.z == 1) ? g1 : g2;
  const int K = 1024;
  const int TN = NB * 32;
  const int m0 = blockIdx.x * 128;
  const int n0 = blockIdx.y * TN;
  const int tid = threadIdx.x;
  const int w = tid >> 6, l = tid & 63, lr = l & 15, lk = l >> 4;
  const int wr = w >> 1, wc = w & 1;

  // double-buffered: A tile 128x32 (fp32 or bf16), B tile TNx32 bf16 — LINEAR layout
  __shared__ __align__(16) char AsRaw[2][128 * 32 * (AF32 ? 4 : 2)];
  __shared__ __align__(16) short Bs[2][TN * 32];

  // read-side swizzle constants
  const int swz3 = lr & 7;                           // fp32 tile: 8 slots of 16B per 128B row
  const int swz2 = (lr & 3) ^ ((lr >> 2) & 3);       // bf16 tile: 4 slots of 16B per 64B row

  f32x4 acc[4][NB];
#pragma unroll
  for (int i = 0; i < 4; ++i)
#pragma unroll
    for (int j = 0; j < NB; ++j) acc[i][j] = (f32x4){0.f, 0.f, 0.f, 0.f};

  auto STAGE = [&](int buf, int k0) {
    if constexpr (AF32) {
      const float* Af = (const float*)g.A;
      float* Asf = (float*)AsRaw[buf];
#pragma unroll
      for (int i = 0; i < 4; ++i) {                // 128x32 fp32 = 1024 16B chunks
        int c = i * 256 + tid;
        int row = c >> 3, s = c & 7;
        int gc = (s ^ (row & 7)) * 4;              // inverse-swizzled source column
        gl2lds16(&Af[(size_t)(m0 + row) * K + k0 + gc], &Asf[c * 4]);
      }
    } else {
      const short* Ah = (const short*)g.A;
      short* As = (short*)AsRaw[buf];
#pragma unroll
      for (int i = 0; i < 2; ++i) {                // 128x32 bf16 = 512 16B chunks
        int c = i * 256 + tid;
        int row = c >> 2, s = c & 3;
        int gc = (s ^ ((row & 3) ^ ((row >> 2) & 3))) * 8;
        gl2lds16(&Ah[(size_t)(m0 + row) * K + k0 + gc], &As[c * 8]);
      }
    }
    const short* Bh = (const short*)g.Bt;
#pragma unroll
    for (int i = 0; i < TN / 64; ++i) {            // TNx32 bf16 = TN*4 16B chunks
      int c = i * 256 + tid;
      int row = c >> 2, s = c & 3;
      int gc = (s ^ ((row & 3) ^ ((row >> 2) & 3))) * 8;
      gl2lds16(&Bh[(size_t)(n0 + row) * K + k0 + gc], &Bs[buf][c * 8]);
    }
  };

  auto COMPUTE = [&](int buf) {
    const float* Asf = (const float*)AsRaw[buf];
    const short* As  = (const short*)AsRaw[buf];
    short8 af[4], bfr[NB];
#pragma unroll
    for (int t = 0; t < 4; ++t) {
      int row = wr * 64 + t * 16 + lr;
      if constexpr (AF32) {
        int base = row * 32;                       // floats
        f32x4 lo = *(const f32x4*)&Asf[base + (((lk << 1)    ) ^ swz3) * 4];
        f32x4 hi = *(const f32x4*)&Asf[base + (((lk << 1) | 1) ^ swz3) * 4];
        af[t] = cvt_pk8(lo, hi);
      } else {
        af[t] = *(const short8*)&As[row * 32 + (lk ^ swz2) * 8];
      }
    }
#pragma unroll
    for (int t = 0; t < NB; ++t) {
      int row = wc * (NB * 16) + t * 16 + lr;
      bfr[t] = *(const short8*)&Bs[buf][row * 32 + (lk ^ swz2) * 8];
    }
#pragma unroll
    for (int ti = 0; ti < 4; ++ti)
#pragma unroll
      for (int tj = 0; tj < NB; ++tj)
        acc[ti][tj] = __builtin_amdgcn_mfma_f32_16x16x32_bf16(af[ti], bfr[tj], acc[ti][tj], 0, 0, 0);
  };

  // ---- 2-phase pipelined main loop (32 K-tiles) ----
  STAGE(0, 0);
  __syncthreads();                 // drain prologue loads
  int cur = 0;
  for (int t = 0; t < 31; ++t) {
    STAGE(cur ^ 1, (t + 1) * 32);  // issue next tile's loads (in flight across compute)
    COMPUTE(cur);
    __syncthreads();               // drains vmcnt(next tile) + lgkm; one barrier per K-step
    cur ^= 1;
  }
  COMPUTE(cur);                    // tail tile, no prefetch

#pragma unroll
  for (int ti = 0; ti < 4; ++ti)
#pragma unroll
    for (int tj = 0; tj < NB; ++tj) {
      int n = n0 + wc * (NB * 16) + tj * 16 + lr;
      float bia = g.bias[n];
      int mb = m0 + wr * 64 + ti * 16 + lk * 4;        // C rows: mb..mb+3
      if (g.mode == 2) {
        bf16x4 o;
#pragma unroll
        for (int r = 0; r < 4; ++r) o[r] = f2bf(acc[ti][tj][r] + bia);
        // [b][h][d][s]: 4 consecutive s -> one 8B store
        *(bf16x4*)&g.out[((mb >> 11) * 16 + (n >> 6)) * (SEQL * HS) + (n & 63) * SEQL + (mb & 2047)] = o;
      } else {
#pragma unroll
        for (int r = 0; r < 4; ++r) {
          int m = mb + r;
          float v = acc[ti][tj][r] + bia;
          if (g.mode == 0) {
            g.out[((m >> 11) * 16 + (n >> 6)) * (SEQL * HS) + (m & 2047) * HS + (n & 63)] = f2bf(v);
          } else {
            g.outf[(size_t)m * DM + n] = v;
          }
        }
      }
    }
}

// ---------------- flash attention (S^T form): per (b,h), O = softmax(Q K^T / 8) V ----------------
// T14 async-STAGE split: K/V tile kv+1's global loads are issued right after the
// ds_write+barrier of tile kv, so HBM latency hides under QK^T/softmax/PV of tile kv.
// launch_bounds (256,3): +32 VGPR of in-flight K/V regs must not spill.
__global__ __launch_bounds__(256, 3) void attn_kernel(const short* __restrict__ Qg, const short* __restrict__ Kg,
                                                      const short* __restrict__ Vtg, short* __restrict__ Og) {
  const int qt = blockIdx.x;   // 32 q-tiles of 64 rows
  const int bh = blockIdx.y;   // 32 (b,h)
  const short* Qp = Qg + bh * SEQL * HS;
  const short* Kp = Kg + bh * SEQL * HS;
  const short* Vp = Vtg + bh * HS * SEQL;   // [d][s]
  const int tid = threadIdx.x, w = tid >> 6, l = tid & 63, lr = l & 15, lk = l >> 4;
  const int qw = qt * 64 + w * 16;          // wave's q base (16 rows)

  __shared__ __align__(16) short Ks[128][72];      // K tile [kv][d]
  __shared__ __align__(16) short Vt[64][136];      // V^T tile [d][kv]

  short8 qf[2];
#pragma unroll
  for (int kk = 0; kk < 2; ++kk) {
    short8 qr = *(const short8*)&Qp[(qw + lr) * HS + kk * 32 + lk * 8];
#pragma unroll
    for (int j = 0; j < 8; ++j) qf[kk][j] = f2bf(bf2f(qr[j]) * 0.125f);
  }

  float mrow = -1e30f, lrow = 0.f;
  f32x4 accO[4];
#pragma unroll
  for (int t = 0; t < 4; ++t) accO[t] = (f32x4){0.f, 0.f, 0.f, 0.f};

  // in-flight K/V tile registers (T14)
  short8 kreg[4], vreg[4];
  auto loadKV = [&](int kv) {
#pragma unroll
    for (int i = 0; i < 4; ++i) {
      int q = tid + i * 256;
      kreg[i] = *(const short8*)&Kp[(kv * 128 + (q >> 3)) * HS + (q & 7) * 8];
      vreg[i] = *(const short8*)&Vp[(q >> 4) * SEQL + kv * 128 + (q & 15) * 8];
    }
  };
  loadKV(0);

  for (int kv = 0; kv < 16; ++kv) {
    __syncthreads();                         // all waves done reading tile kv-1
#pragma unroll
    for (int i = 0; i < 4; ++i) {            // write tile kv from regs (vmcnt auto-waited)
      int q = tid + i * 256;
      *(short8*)&Ks[q >> 3][(q & 7) * 8] = kreg[i];
      *(short8*)&Vt[q >> 4][(q & 15) * 8] = vreg[i];
    }
    __syncthreads();
    if (kv < 15) loadKV(kv + 1);             // issue next tile's loads; hide under compute

    f32x4 accS[8];
#pragma unroll
    for (int tj = 0; tj < 8; ++tj) {
      short8 a0 = *(const short8*)&Ks[tj * 16 + lr][lk * 8];
      short8 a1 = *(const short8*)&Ks[tj * 16 + lr][32 + lk * 8];
      f32x4 z = (f32x4){0.f, 0.f, 0.f, 0.f};
      z = __builtin_amdgcn_mfma_f32_16x16x32_bf16(a0, qf[0], z, 0, 0, 0);
      accS[tj] = __builtin_amdgcn_mfma_f32_16x16x32_bf16(a1, qf[1], z, 0, 0, 0);
    }

    float mx = accS[0][0];
#pragma unroll
    for (int tj = 0; tj < 8; ++tj)
#pragma unroll
      for (int r = 0; r < 4; ++r) mx = fmaxf(mx, accS[tj][r]);
    mx = fmaxf(mx, __shfl_xor(mx, 16));
    mx = fmaxf(mx, __shfl_xor(mx, 32));
    float mn = fmaxf(mrow, mx);
    float alpha = __expf(mrow - mn);
    float ps = 0.f;
#pragma unroll
    for (int tj = 0; tj < 8; ++tj)
#pragma unroll
      for (int r = 0; r < 4; ++r) {
        float p = __expf(accS[tj][r] - mn);
        accS[tj][r] = p;
        ps += p;
      }
    ps += __shfl_xor(ps, 16);
    ps += __shfl_xor(ps, 32);
    lrow = lrow * alpha + ps;
    mrow = mn;
#pragma unroll
    for (int t = 0; t < 4; ++t) accO[t] *= alpha;

#pragma unroll
    for (int st = 0; st < 8; ++st) {
      bf16x4 bfrag;
#pragma unroll
      for (int r = 0; r < 4; ++r) bfrag[r] = f2bf(accS[st][r]);
#pragma unroll
      for (int tjd = 0; tjd < 4; ++tjd) {
        bf16x4 afrag = *(const bf16x4*)&Vt[tjd * 16 + lr][st * 16 + lk * 4];
        accO[tjd] = __builtin_amdgcn_mfma_f32_16x16x16bf16_1k(afrag, bfrag, accO[tjd], 0, 0, 0);
      }
    }
  }

  const int b = bh >> 4, h = bh & 15;
  float inv = 1.f / lrow;
  size_t rowbase = (size_t)(b * SEQL + qw + lr) * DM + h * HS;
#pragma unroll
  for (int tjd = 0; tjd < 4; ++tjd) {
    bf16x4 o;
#pragma unroll
    for (int r = 0; r < 4; ++r) o[r] = f2bf(accO[tjd][r] * inv);
    *(bf16x4*)&Og[rowbase + tjd * 16 + lk * 4] = o;
  }
}

extern "C" void kernel_launch(void* const* d_in, const int* in_sizes, int n_in,
                              void* d_out, int out_size, void* d_ws, size_t ws_size,
                              hipStream_t stream) {
  const float* query  = (const float*)d_in[0];
  const float* key_in = (const float*)d_in[1];
  const float* value  = (const float*)d_in[2];
  const float* Wq = (const float*)d_in[3];
  const float* Wk = (const float*)d_in[4];
  const float* Wv = (const float*)d_in[5];
  const float* bq = (const float*)d_in[6];
  const float* bk = (const float*)d_in[7];
  const float* bv = (const float*)d_in[8];
  const float* Wo = (const float*)d_in[9];
  const float* bo = (const float*)d_in[10];
  float* out = (float*)d_out;          // FP32 output

  // ws layout (shorts), 32 MB total:
  //   [0,4M) Qb [b][h][s][64]  (reused as Wob bf16 after attn);
  //   [4M,8M) Kb; [8M,12M) Vbt [b][h][64][s];
  //   [12M,16M) X: WtQ/WtK/WtV (QKV-GEMM phase) then At [4096][1024] (attn phase)
  short* ws  = (short*)d_ws;
  short* Qb  = ws;
  short* Kb  = Qb + (4 << 20);
  short* Vbt = Kb + (4 << 20);
  short* X   = Vbt + (4 << 20);
  short* WtQ = X;
  short* WtK = WtQ + (1 << 20);
  short* WtV = WtK + (1 << 20);
  short* At  = X;
  short* Wob = Qb;                     // Qb is dead once attn completes

  pack_w_kernel<<<dim3(16, 16, 3), 256, 0, stream>>>(Wq, Wk, Wv, WtQ, WtK, WtV);

  GemmArgs gq{query, WtQ, bq, Qb, nullptr, 0}, gk{key_in, WtK, bk, Kb, nullptr, 0},
           gv{value, WtV, bv, Vbt, nullptr, 2};
  gemm_bt_kernel<true, 4><<<dim3(32, 8, 3), 256, 0, stream>>>(gq, gk, gv);

  attn_kernel<<<dim3(32, 32), 256, 0, stream>>>(Qb, Kb, Vbt, At);

  cvt_bf16_kernel<<<dim3(512), 256, 0, stream>>>(Wo, Wob);   // 1M elems -> bf16

  GemmArgs go{At, Wob, bo, nullptr, out, 1};
  gemm_bt_kernel<false, 2><<<dim3(32, 16, 1), 256, 0, stream>>>(go, go, go);
}